// Round 20
// baseline (154.945 us; speedup 1.0000x reference)
//
#include <hip/hip_runtime.h>
#include <hip/hip_fp16.h>
#include <math.h>

static constexpr int TPB = 256;
static constexpr int NPB_SHIFT = 8;   // 256 nodes per bucket
static constexpr int BCAP = 5120;     // fixed bucket region; Poisson(4096) + 16 sigma
static constexpr int PCHUNK = 4096;   // edges per partition block (16/thread)

// pk = (src << 15) | (fp16_bits(ew) & 0x7FFF)   [ew >= 0, sign bit 0]
__device__ __forceinline__ int p_src(unsigned p) { return (int)(p >> 15); }
__device__ __forceinline__ float p_w(unsigned p) {
  return __half2float(__ushort_as_half((unsigned short)(p & 0x7FFFu)));
}

struct h2x4 { __half2 a, b, c, d; };  // 16B row slice

__device__ __forceinline__ __half2 shfl_h2(__half2 v, int mask) {
  int b = *reinterpret_cast<int*>(&v);
  int r = __shfl_xor(b, mask, 64);
  return *reinterpret_cast<__half2*>(&r);
}

// Each block bins PCHUNK edges into FIXED bucket regions [b*BCAP, b*BCAP+BCAP):
// LDS histogram -> one global atomic per touched bucket (private range) -> contiguous runs.
__global__ void k_partition(const int* __restrict__ src, const int* __restrict__ dst,
                            const float* __restrict__ ew, int* __restrict__ bkcnt,
                            unsigned* __restrict__ ppk, unsigned char* __restrict__ pld,
                            int E, int NB) {
  __shared__ int lh[512];
  __shared__ int lbase[512];
  __shared__ int lcur[512];
  int tid = threadIdx.x;
  long long e0 = (long long)blockIdx.x * PCHUNK;
  int d[PCHUNK / TPB];
  unsigned pk[PCHUNK / TPB];
  for (int t = tid; t < NB; t += TPB) { lh[t] = 0; lcur[t] = 0; }
  __syncthreads();
#pragma unroll
  for (int r = 0; r < PCHUNK / TPB; ++r) {
    long long e = e0 + (long long)r * TPB + tid;
    if (e < E) {
      d[r] = dst[e];
      pk[r] = ((unsigned)src[e] << 15) |
              ((unsigned)__half_as_ushort(__float2half(ew[e])) & 0x7FFFu);
      atomicAdd(&lh[d[r] >> NPB_SHIFT], 1);
    } else {
      d[r] = -1;
    }
  }
  __syncthreads();
  for (int t = tid; t < NB; t += TPB)
    lbase[t] = lh[t] ? (t * BCAP + atomicAdd(&bkcnt[t], lh[t])) : 0;
  __syncthreads();
#pragma unroll
  for (int r = 0; r < PCHUNK / TPB; ++r) {
    if (d[r] >= 0) {
      int b = d[r] >> NPB_SHIFT;
      int pos = atomicAdd(&lcur[b], 1);
      size_t gp = (size_t)lbase[b] + pos;   // run stays inside region (16-sigma margin)
      ppk[gp] = pk[r];
      pld[gp] = (unsigned char)(d[r] & 255);
    }
  }
}

// One block per bucket: group edges by node -> CSR (rc = {abs offset, cnt}), deg -> dis,
// fused GEMM1+scale: hh = fp16(dis * (x @ W1)), and a counting-sort by degree producing
// gord: per-bucket descending-degree node order (wave-level load balance for gathers).
__global__ void __launch_bounds__(TPB) k_bucket(const unsigned* __restrict__ ppk,
                                                const unsigned char* __restrict__ pld,
                                                const int* __restrict__ bkcnt,
                                                unsigned* __restrict__ csr,
                                                int2* __restrict__ rc,
                                                float* __restrict__ dis,
                                                const float* __restrict__ x,
                                                const float* __restrict__ W1,
                                                __half2* __restrict__ hh,
                                                int* __restrict__ gord, int n) {
  __shared__ unsigned lpk[BCAP];       // 20 KB
  __shared__ unsigned char lld[BCAP];  // 5 KB
  __shared__ float sW[45 * 32];        // 5.6 KB
  __shared__ int lcnt[256];
  __shared__ int lofs[256];
  __shared__ float lsum[256];
  __shared__ int dbin[64];
  __shared__ int dbase[64];
  int b = blockIdx.x;
  int t = threadIdx.x;
  int beg = b * BCAP;
  int m = bkcnt[b];
  if (m > BCAP) m = BCAP;  // statistically impossible
  lcnt[t] = 0;
  lsum[t] = 0.f;
  if (t < 64) dbin[t] = 0;
  for (int i = t; i < 45 * 32; i += TPB) sW[i] = W1[i];
  __syncthreads();
  for (int i = t; i < m; i += TPB) {
    unsigned pk = ppk[(size_t)beg + i];
    unsigned char ld = pld[(size_t)beg + i];
    lpk[i] = pk;
    lld[i] = ld;
    atomicAdd(&lcnt[ld], 1);
  }
  __syncthreads();
  int v = lcnt[t];
  lofs[t] = v;
  __syncthreads();
  for (int off = 1; off < 256; off <<= 1) {  // inclusive scan
    int tv = (t >= off) ? lofs[t - off] : 0;
    __syncthreads();
    lofs[t] += tv;
    __syncthreads();
  }
  int ex = lofs[t] - v;  // exclusive
  int gnode = (b << NPB_SHIFT) + t;
  if (gnode < n) rc[gnode] = make_int2(beg + ex, v);
  int vv = (gnode < n) ? (min(v, 62) + 1) : 0;  // degree bin (0 = invalid, sorts last)
  atomicAdd(&dbin[vv], 1);
  lcnt[t] = ex;  // reuse as intra-bucket cursor
  __syncthreads();
  if (t == 0) {  // descending exclusive scan: dbase[d] = count of entries in bins > d
    int run = 0;
    for (int d2 = 63; d2 >= 0; --d2) { dbase[d2] = run; run += dbin[d2]; }
  }
  for (int i = t; i < m; i += TPB) {
    unsigned pk = lpk[i];
    int ld = lld[i];
    int pos = atomicAdd(&lcnt[ld], 1);
    csr[(size_t)beg + pos] = pk;   // single-writer 20KB region: L2-resident
    atomicAdd(&lsum[ld], p_w(pk));
  }
  __syncthreads();
  int rnk = atomicAdd(&dbase[vv], 1);
  gord[(b << NPB_SHIFT) + rnk] = (gnode < n) ? gnode : -1;
  if (gnode < n) {
    float dsc = rsqrtf(1.0f + lsum[t]);
    dis[gnode] = dsc;
    float xr[45];
#pragma unroll
    for (int k = 0; k < 45; ++k) xr[k] = x[(size_t)gnode * 45 + k];
    __half2* hw = hh + (size_t)gnode * 16;
#pragma unroll 2
    for (int j2 = 0; j2 < 16; ++j2) {
      float a0 = 0.f, a1 = 0.f;
#pragma unroll
      for (int k = 0; k < 45; ++k) {
        a0 = fmaf(xr[k], sW[k * 32 + j2 * 2], a0);
        a1 = fmaf(xr[k], sW[k * 32 + j2 * 2 + 1], a1);
      }
      hw[j2] = __floats2half2_rn(a0 * dsc, a1 * dsc);
    }
  }
}

// Layer-1 gather: 4 lanes/node, lane owns 16B slice, scans whole row unroll-4.
// Nodes processed in degree-sorted order via gord (wave-uniform work).
__global__ void k_gather1(const unsigned* __restrict__ csr, const int2* __restrict__ rc,
                          const float* __restrict__ dis, const __half2* __restrict__ hh,
                          const float* __restrict__ b1, __half2* __restrict__ outv,
                          const int* __restrict__ gord, int NT) {
  int gid = blockIdx.x * blockDim.x + threadIdx.x;
  int i = gid >> 2;
  if (i >= NT) return;
  int node = gord[i];
  if (node < 0) return;
  int q = (threadIdx.x & 3) * 4;          // this lane's half2 base (8 features)
  int2 r = rc[node];
  const unsigned* row = csr + r.x;
  int m = r.y;
  const __half2* tbl = hh + q;
  float2 c0 = {0.f, 0.f}, c1 = {0.f, 0.f}, c2 = {0.f, 0.f}, c3 = {0.f, 0.f};
  float2 d0 = {0.f, 0.f}, d1 = {0.f, 0.f}, d2 = {0.f, 0.f}, d3 = {0.f, 0.f};
  int e = 0;
  for (; e + 3 < m; e += 4) {
    unsigned p0 = row[e], p1 = row[e + 1], p2 = row[e + 2], p3 = row[e + 3];
    h2x4 v0 = *reinterpret_cast<const h2x4*>(tbl + (size_t)p_src(p0) * 16);
    h2x4 v1 = *reinterpret_cast<const h2x4*>(tbl + (size_t)p_src(p1) * 16);
    h2x4 v2 = *reinterpret_cast<const h2x4*>(tbl + (size_t)p_src(p2) * 16);
    h2x4 v3 = *reinterpret_cast<const h2x4*>(tbl + (size_t)p_src(p3) * 16);
    float w0 = p_w(p0), w1 = p_w(p1), w2 = p_w(p2), w3 = p_w(p3);
    float2 f;
    f = __half22float2(v0.a); c0.x = fmaf(w0, f.x, c0.x); c0.y = fmaf(w0, f.y, c0.y);
    f = __half22float2(v0.b); c1.x = fmaf(w0, f.x, c1.x); c1.y = fmaf(w0, f.y, c1.y);
    f = __half22float2(v0.c); c2.x = fmaf(w0, f.x, c2.x); c2.y = fmaf(w0, f.y, c2.y);
    f = __half22float2(v0.d); c3.x = fmaf(w0, f.x, c3.x); c3.y = fmaf(w0, f.y, c3.y);
    f = __half22float2(v1.a); d0.x = fmaf(w1, f.x, d0.x); d0.y = fmaf(w1, f.y, d0.y);
    f = __half22float2(v1.b); d1.x = fmaf(w1, f.x, d1.x); d1.y = fmaf(w1, f.y, d1.y);
    f = __half22float2(v1.c); d2.x = fmaf(w1, f.x, d2.x); d2.y = fmaf(w1, f.y, d2.y);
    f = __half22float2(v1.d); d3.x = fmaf(w1, f.x, d3.x); d3.y = fmaf(w1, f.y, d3.y);
    f = __half22float2(v2.a); c0.x = fmaf(w2, f.x, c0.x); c0.y = fmaf(w2, f.y, c0.y);
    f = __half22float2(v2.b); c1.x = fmaf(w2, f.x, c1.x); c1.y = fmaf(w2, f.y, c1.y);
    f = __half22float2(v2.c); c2.x = fmaf(w2, f.x, c2.x); c2.y = fmaf(w2, f.y, c2.y);
    f = __half22float2(v2.d); c3.x = fmaf(w2, f.x, c3.x); c3.y = fmaf(w2, f.y, c3.y);
    f = __half22float2(v3.a); d0.x = fmaf(w3, f.x, d0.x); d0.y = fmaf(w3, f.y, d0.y);
    f = __half22float2(v3.b); d1.x = fmaf(w3, f.x, d1.x); d1.y = fmaf(w3, f.y, d1.y);
    f = __half22float2(v3.c); d2.x = fmaf(w3, f.x, d2.x); d2.y = fmaf(w3, f.y, d2.y);
    f = __half22float2(v3.d); d3.x = fmaf(w3, f.x, d3.x); d3.y = fmaf(w3, f.y, d3.y);
  }
  for (; e < m; ++e) {
    unsigned p = row[e];
    h2x4 v = *reinterpret_cast<const h2x4*>(tbl + (size_t)p_src(p) * 16);
    float w = p_w(p);
    float2 f;
    f = __half22float2(v.a); c0.x = fmaf(w, f.x, c0.x); c0.y = fmaf(w, f.y, c0.y);
    f = __half22float2(v.b); c1.x = fmaf(w, f.x, c1.x); c1.y = fmaf(w, f.y, c1.y);
    f = __half22float2(v.c); c2.x = fmaf(w, f.x, c2.x); c2.y = fmaf(w, f.y, c2.y);
    f = __half22float2(v.d); c3.x = fmaf(w, f.x, c3.x); c3.y = fmaf(w, f.y, c3.y);
  }
  c0.x += d0.x; c0.y += d0.y; c1.x += d1.x; c1.y += d1.y;
  c2.x += d2.x; c2.y += d2.y; c3.x += d3.x; c3.y += d3.y;
  float dd = dis[node];
  h2x4 own = *reinterpret_cast<const h2x4*>(hh + (size_t)node * 16 + q);
  __half2* op = outv + (size_t)node * 16 + q;
  float2 o0 = __half22float2(own.a), o1 = __half22float2(own.b);
  float2 o2 = __half22float2(own.c), o3 = __half22float2(own.d);
  const float4* bp = reinterpret_cast<const float4*>(b1 + q * 2);
  float4 ba = bp[0], bb = bp[1];
  op[0] = __floats2half2_rn(dd * tanhf(ba.x + dd * (c0.x + o0.x)),
                            dd * tanhf(ba.y + dd * (c0.y + o0.y)));
  op[1] = __floats2half2_rn(dd * tanhf(ba.z + dd * (c1.x + o1.x)),
                            dd * tanhf(ba.w + dd * (c1.y + o1.y)));
  op[2] = __floats2half2_rn(dd * tanhf(bb.x + dd * (c2.x + o2.x)),
                            dd * tanhf(bb.y + dd * (c2.y + o2.y)));
  op[3] = __floats2half2_rn(dd * tanhf(bb.z + dd * (c3.x + o3.x)),
                            dd * tanhf(bb.w + dd * (c3.y + o3.y)));
}

// Layer-2 gather FUSED with GEMM2, degree-sorted order: gather y (4 lanes/node),
// shfl-share y within the 4-lane group, then out = y@W2 + b2.
__global__ void k_gather2g(const unsigned* __restrict__ csr, const int2* __restrict__ rc,
                           const float* __restrict__ dis, const __half2* __restrict__ hh,
                           const float* __restrict__ W2, const float* __restrict__ b2,
                           float* __restrict__ out, const int* __restrict__ gord, int NT) {
  __shared__ float sW[32 * 128];  // 16 KB
  __shared__ float sB[128];
  for (int t = threadIdx.x; t < 32 * 128; t += blockDim.x) sW[t] = W2[t];
  if (threadIdx.x < 128) sB[threadIdx.x] = b2[threadIdx.x];
  __syncthreads();
  int gid = blockIdx.x * blockDim.x + threadIdx.x;
  int i = gid >> 2;
  if (i >= NT) return;
  int node = gord[i];
  if (node < 0) return;
  int lq = threadIdx.x & 3;               // lane's quarter
  int q = lq * 4;                         // half2 base
  int2 r = rc[node];
  const unsigned* row = csr + r.x;
  int m = r.y;
  const __half2* tbl = hh + q;
  float2 c0 = {0.f, 0.f}, c1 = {0.f, 0.f}, c2 = {0.f, 0.f}, c3 = {0.f, 0.f};
  float2 d0 = {0.f, 0.f}, d1 = {0.f, 0.f}, d2 = {0.f, 0.f}, d3 = {0.f, 0.f};
  int e = 0;
  for (; e + 3 < m; e += 4) {
    unsigned p0 = row[e], p1 = row[e + 1], p2 = row[e + 2], p3 = row[e + 3];
    h2x4 v0 = *reinterpret_cast<const h2x4*>(tbl + (size_t)p_src(p0) * 16);
    h2x4 v1 = *reinterpret_cast<const h2x4*>(tbl + (size_t)p_src(p1) * 16);
    h2x4 v2 = *reinterpret_cast<const h2x4*>(tbl + (size_t)p_src(p2) * 16);
    h2x4 v3 = *reinterpret_cast<const h2x4*>(tbl + (size_t)p_src(p3) * 16);
    float w0 = p_w(p0), w1 = p_w(p1), w2 = p_w(p2), w3 = p_w(p3);
    float2 f;
    f = __half22float2(v0.a); c0.x = fmaf(w0, f.x, c0.x); c0.y = fmaf(w0, f.y, c0.y);
    f = __half22float2(v0.b); c1.x = fmaf(w0, f.x, c1.x); c1.y = fmaf(w0, f.y, c1.y);
    f = __half22float2(v0.c); c2.x = fmaf(w0, f.x, c2.x); c2.y = fmaf(w0, f.y, c2.y);
    f = __half22float2(v0.d); c3.x = fmaf(w0, f.x, c3.x); c3.y = fmaf(w0, f.y, c3.y);
    f = __half22float2(v1.a); d0.x = fmaf(w1, f.x, d0.x); d0.y = fmaf(w1, f.y, d0.y);
    f = __half22float2(v1.b); d1.x = fmaf(w1, f.x, d1.x); d1.y = fmaf(w1, f.y, d1.y);
    f = __half22float2(v1.c); d2.x = fmaf(w1, f.x, d2.x); d2.y = fmaf(w1, f.y, d2.y);
    f = __half22float2(v1.d); d3.x = fmaf(w1, f.x, d3.x); d3.y = fmaf(w1, f.y, d3.y);
    f = __half22float2(v2.a); c0.x = fmaf(w2, f.x, c0.x); c0.y = fmaf(w2, f.y, c0.y);
    f = __half22float2(v2.b); c1.x = fmaf(w2, f.x, c1.x); c1.y = fmaf(w2, f.y, c1.y);
    f = __half22float2(v2.c); c2.x = fmaf(w2, f.x, c2.x); c2.y = fmaf(w2, f.y, c2.y);
    f = __half22float2(v2.d); c3.x = fmaf(w2, f.x, c3.x); c3.y = fmaf(w2, f.y, c3.y);
    f = __half22float2(v3.a); d0.x = fmaf(w3, f.x, d0.x); d0.y = fmaf(w3, f.y, d0.y);
    f = __half22float2(v3.b); d1.x = fmaf(w3, f.x, d1.x); d1.y = fmaf(w3, f.y, d1.y);
    f = __half22float2(v3.c); d2.x = fmaf(w3, f.x, d2.x); d2.y = fmaf(w3, f.y, d2.y);
    f = __half22float2(v3.d); d3.x = fmaf(w3, f.x, d3.x); d3.y = fmaf(w3, f.y, d3.y);
  }
  for (; e < m; ++e) {
    unsigned p = row[e];
    h2x4 v = *reinterpret_cast<const h2x4*>(tbl + (size_t)p_src(p) * 16);
    float w = p_w(p);
    float2 f;
    f = __half22float2(v.a); c0.x = fmaf(w, f.x, c0.x); c0.y = fmaf(w, f.y, c0.y);
    f = __half22float2(v.b); c1.x = fmaf(w, f.x, c1.x); c1.y = fmaf(w, f.y, c1.y);
    f = __half22float2(v.c); c2.x = fmaf(w, f.x, c2.x); c2.y = fmaf(w, f.y, c2.y);
    f = __half22float2(v.d); c3.x = fmaf(w, f.x, c3.x); c3.y = fmaf(w, f.y, c3.y);
  }
  float dd = dis[node];
  h2x4 own = *reinterpret_cast<const h2x4*>(hh + (size_t)node * 16 + q);
  float2 o0 = __half22float2(own.a), o1 = __half22float2(own.b);
  float2 o2 = __half22float2(own.c), o3 = __half22float2(own.d);
  __half2 y0 = __floats2half2_rn(dd * (c0.x + d0.x + o0.x), dd * (c0.y + d0.y + o0.y));
  __half2 y1 = __floats2half2_rn(dd * (c1.x + d1.x + o1.x), dd * (c1.y + d1.y + o1.y));
  __half2 y2 = __floats2half2_rn(dd * (c2.x + d2.x + o2.x), dd * (c2.y + d2.y + o2.y));
  __half2 y3 = __floats2half2_rn(dd * (c3.x + d3.x + o3.x), dd * (c3.y + d3.y + o3.y));
  __half2 g1_0 = shfl_h2(y0, 1), g1_1 = shfl_h2(y1, 1), g1_2 = shfl_h2(y2, 1), g1_3 = shfl_h2(y3, 1);
  __half2 g2_0 = shfl_h2(y0, 2), g2_1 = shfl_h2(y1, 2), g2_2 = shfl_h2(y2, 2), g2_3 = shfl_h2(y3, 2);
  __half2 g3_0 = shfl_h2(y0, 3), g3_1 = shfl_h2(y1, 3), g3_2 = shfl_h2(y2, 3), g3_3 = shfl_h2(y3, 3);
  int g4 = lq * 4;  // output float4 base; chunks at j = g4 + qq*16 (conflict-free)
  float4 a[8];
#pragma unroll
  for (int qq = 0; qq < 8; ++qq) a[qq] = *reinterpret_cast<const float4*>(&sB[g4 + qq * 16]);
#define GEMM_GRP(kb, h0, h1, h2v, h3v)                                              \
  {                                                                                 \
    __half2 hv[4] = {h0, h1, h2v, h3v};                                             \
    _Pragma("unroll") for (int ii = 0; ii < 4; ++ii) {                              \
      float2 yv = __half22float2(hv[ii]);                                           \
      const float* w0 = &sW[((kb + ii) * 2) * 128 + g4];                            \
      const float* w1 = &sW[((kb + ii) * 2 + 1) * 128 + g4];                        \
      _Pragma("unroll") for (int qq = 0; qq < 8; ++qq) {                            \
        float4 wa = *reinterpret_cast<const float4*>(w0 + qq * 16);                 \
        float4 wb = *reinterpret_cast<const float4*>(w1 + qq * 16);                 \
        a[qq].x = fmaf(yv.x, wa.x, fmaf(yv.y, wb.x, a[qq].x));                      \
        a[qq].y = fmaf(yv.x, wa.y, fmaf(yv.y, wb.y, a[qq].y));                      \
        a[qq].z = fmaf(yv.x, wa.z, fmaf(yv.y, wb.z, a[qq].z));                      \
        a[qq].w = fmaf(yv.x, wa.w, fmaf(yv.y, wb.w, a[qq].w));                      \
      }                                                                             \
    }                                                                               \
  }
  GEMM_GRP(lq * 4, y0, y1, y2, y3)
  GEMM_GRP((lq ^ 1) * 4, g1_0, g1_1, g1_2, g1_3)
  GEMM_GRP((lq ^ 2) * 4, g2_0, g2_1, g2_2, g2_3)
  GEMM_GRP((lq ^ 3) * 4, g3_0, g3_1, g3_2, g3_3)
#undef GEMM_GRP
  float* op = out + (size_t)node * 128 + g4;
#pragma unroll
  for (int qq = 0; qq < 8; ++qq) *reinterpret_cast<float4*>(op + qq * 16) = a[qq];
}

static inline dim3 gx(long long work) { return dim3((unsigned)((work + TPB - 1) / TPB)); }

extern "C" void kernel_launch(void* const* d_in, const int* in_sizes, int n_in,
                              void* d_out, int out_size, void* d_ws, size_t ws_size,
                              hipStream_t stream) {
  const float* x   = (const float*)d_in[0];
  const int*   src = (const int*)d_in[1];
  const int*   dst = (const int*)d_in[2];
  const float* ew  = (const float*)d_in[3];
  const float* W1  = (const float*)d_in[4];
  const float* b1  = (const float*)d_in[5];
  const float* W2  = (const float*)d_in[6];
  const float* b2  = (const float*)d_in[7];
  float* out = (float*)d_out;

  const int n = in_sizes[0] / 45;  // 100000
  const int E = in_sizes[1];       // 1600000
  const int NB = (n + 255) >> NPB_SHIFT;  // 391 (<= 512)
  const int NT = NB << NPB_SHIFT;         // padded node-slot count

  char* w = (char*)d_ws;
  size_t o = 0;
  auto alloc = [&](size_t bytes) { void* p = w + o; o += ((bytes + 255) & ~(size_t)255); return p; };
  int*           bkcnt = (int*)          alloc((size_t)NB * 4);
  unsigned*      ppk   = (unsigned*)     alloc((size_t)NB * BCAP * 4);  // 8 MB padded
  unsigned char* pld   = (unsigned char*)alloc((size_t)NB * BCAP);      // 2 MB padded
  unsigned*      csr   = (unsigned*)     alloc((size_t)NB * BCAP * 4);  // 8 MB padded
  int2*          rc    = (int2*)         alloc((size_t)n * 8);
  float*         dis   = (float*)        alloc((size_t)n * 4);
  int*           gord  = (int*)          alloc((size_t)NT * 4);         // degree-sorted order
  __half2*       hh    = (__half2*)      alloc((size_t)n * 32 * 2);     // 6.4 MB
  __half2*       ag1   = (__half2*)      alloc((size_t)n * 32 * 2);     // 6.4 MB

  const int PB = (E + PCHUNK - 1) / PCHUNK;     // 391

  hipMemsetAsync(bkcnt, 0, (size_t)NB * 4, stream);
  k_partition<<<PB, TPB, 0, stream>>>(src, dst, ew, bkcnt, ppk, pld, E, NB);
  k_bucket<<<NB, TPB, 0, stream>>>(ppk, pld, bkcnt, csr, rc, dis, x, W1, hh, gord, n);
  k_gather1<<<gx((long long)NT * 4), TPB, 0, stream>>>(csr, rc, dis, hh, b1, ag1, gord, NT);
  k_gather2g<<<gx((long long)NT * 4), TPB, 0, stream>>>(csr, rc, dis, ag1, W2, b2, out, gord, NT);
}

// Round 21
// 139.290 us; speedup vs baseline: 1.1124x; 1.1124x over previous
//
#include <hip/hip_runtime.h>
#include <hip/hip_fp16.h>
#include <math.h>

static constexpr int TPB = 256;
static constexpr int NPB_SHIFT = 8;   // 256 nodes per bucket
static constexpr int BCAP = 5120;     // fixed bucket region; Poisson(4096) + 16 sigma
static constexpr int PCHUNK = 4096;   // edges per partition block (16/thread)
static constexpr int PF = 16;         // csr register-prefetch depth (covers ~57% of rows fully)

// pk = (src << 15) | (fp16_bits(ew) & 0x7FFF)   [ew >= 0, sign bit 0]
__device__ __forceinline__ int p_src(unsigned p) { return (int)(p >> 15); }
__device__ __forceinline__ float p_w(unsigned p) {
  return __half2float(__ushort_as_half((unsigned short)(p & 0x7FFFu)));
}

struct h2x4 { __half2 a, b, c, d; };  // 16B row slice

__device__ __forceinline__ __half2 shfl_h2(__half2 v, int mask) {
  int b = *reinterpret_cast<int*>(&v);
  int r = __shfl_xor(b, mask, 64);
  return *reinterpret_cast<__half2*>(&r);
}

// Each block bins PCHUNK edges into FIXED bucket regions [b*BCAP, b*BCAP+BCAP):
// LDS histogram -> one global atomic per touched bucket (private range) -> contiguous runs.
__global__ void k_partition(const int* __restrict__ src, const int* __restrict__ dst,
                            const float* __restrict__ ew, int* __restrict__ bkcnt,
                            unsigned* __restrict__ ppk, unsigned char* __restrict__ pld,
                            int E, int NB) {
  __shared__ int lh[512];
  __shared__ int lbase[512];
  __shared__ int lcur[512];
  int tid = threadIdx.x;
  long long e0 = (long long)blockIdx.x * PCHUNK;
  int d[PCHUNK / TPB];
  unsigned pk[PCHUNK / TPB];
  for (int t = tid; t < NB; t += TPB) { lh[t] = 0; lcur[t] = 0; }
  __syncthreads();
#pragma unroll
  for (int r = 0; r < PCHUNK / TPB; ++r) {
    long long e = e0 + (long long)r * TPB + tid;
    if (e < E) {
      d[r] = dst[e];
      pk[r] = ((unsigned)src[e] << 15) |
              ((unsigned)__half_as_ushort(__float2half(ew[e])) & 0x7FFFu);
      atomicAdd(&lh[d[r] >> NPB_SHIFT], 1);
    } else {
      d[r] = -1;
    }
  }
  __syncthreads();
  for (int t = tid; t < NB; t += TPB)
    lbase[t] = lh[t] ? (t * BCAP + atomicAdd(&bkcnt[t], lh[t])) : 0;
  __syncthreads();
#pragma unroll
  for (int r = 0; r < PCHUNK / TPB; ++r) {
    if (d[r] >= 0) {
      int b = d[r] >> NPB_SHIFT;
      int pos = atomicAdd(&lcur[b], 1);
      size_t gp = (size_t)lbase[b] + pos;   // run stays inside region (16-sigma margin)
      ppk[gp] = pk[r];
      pld[gp] = (unsigned char)(d[r] & 255);
    }
  }
}

// One block per bucket: group edges by node -> CSR (rc = {abs offset, cnt}), deg -> dis,
// and fused GEMM1+scale: hh = fp16(dis * (x @ W1)) for the bucket's 256 nodes.
__global__ void __launch_bounds__(TPB) k_bucket(const unsigned* __restrict__ ppk,
                                                const unsigned char* __restrict__ pld,
                                                const int* __restrict__ bkcnt,
                                                unsigned* __restrict__ csr,
                                                int2* __restrict__ rc,
                                                float* __restrict__ dis,
                                                const float* __restrict__ x,
                                                const float* __restrict__ W1,
                                                __half2* __restrict__ hh, int n) {
  __shared__ unsigned lpk[BCAP];       // 20 KB
  __shared__ unsigned char lld[BCAP];  // 5 KB
  __shared__ float sW[45 * 32];        // 5.6 KB
  __shared__ int lcnt[256];
  __shared__ int lofs[256];
  __shared__ float lsum[256];
  int b = blockIdx.x;
  int t = threadIdx.x;
  int beg = b * BCAP;
  int m = bkcnt[b];
  if (m > BCAP) m = BCAP;  // statistically impossible
  lcnt[t] = 0;
  lsum[t] = 0.f;
  for (int i = t; i < 45 * 32; i += TPB) sW[i] = W1[i];
  __syncthreads();
  for (int i = t; i < m; i += TPB) {
    unsigned pk = ppk[(size_t)beg + i];
    unsigned char ld = pld[(size_t)beg + i];
    lpk[i] = pk;
    lld[i] = ld;
    atomicAdd(&lcnt[ld], 1);
  }
  __syncthreads();
  int v = lcnt[t];
  lofs[t] = v;
  __syncthreads();
  for (int off = 1; off < 256; off <<= 1) {  // inclusive scan
    int tv = (t >= off) ? lofs[t - off] : 0;
    __syncthreads();
    lofs[t] += tv;
    __syncthreads();
  }
  int ex = lofs[t] - v;  // exclusive
  int gnode = (b << NPB_SHIFT) + t;
  if (gnode < n) rc[gnode] = make_int2(beg + ex, v);
  lcnt[t] = ex;  // reuse as intra-bucket cursor
  __syncthreads();
  for (int i = t; i < m; i += TPB) {
    unsigned pk = lpk[i];
    int ld = lld[i];
    int pos = atomicAdd(&lcnt[ld], 1);
    csr[(size_t)beg + pos] = pk;   // single-writer 20KB region: L2-resident
    atomicAdd(&lsum[ld], p_w(pk));
  }
  __syncthreads();
  if (gnode < n) {
    float dsc = rsqrtf(1.0f + lsum[t]);
    dis[gnode] = dsc;
    float xr[45];
#pragma unroll
    for (int k = 0; k < 45; ++k) xr[k] = x[(size_t)gnode * 45 + k];
    __half2* hw = hh + (size_t)gnode * 16;
#pragma unroll 2
    for (int j2 = 0; j2 < 16; ++j2) {
      float a0 = 0.f, a1 = 0.f;
#pragma unroll
      for (int k = 0; k < 45; ++k) {
        a0 = fmaf(xr[k], sW[k * 32 + j2 * 2], a0);
        a1 = fmaf(xr[k], sW[k * 32 + j2 * 2 + 1], a1);
      }
      hw[j2] = __floats2half2_rn(a0 * dsc, a1 * dsc);
    }
  }
}

// Accumulate macro shared by both gathers: one edge (pk) into bank (cc0..cc3).
#define ACC_EDGE(pk, cc0, cc1, cc2, cc3)                                             \
  {                                                                                  \
    h2x4 v = *reinterpret_cast<const h2x4*>(tbl + (size_t)p_src(pk) * 16);           \
    float w = p_w(pk);                                                               \
    float2 f;                                                                        \
    f = __half22float2(v.a); cc0.x = fmaf(w, f.x, cc0.x); cc0.y = fmaf(w, f.y, cc0.y); \
    f = __half22float2(v.b); cc1.x = fmaf(w, f.x, cc1.x); cc1.y = fmaf(w, f.y, cc1.y); \
    f = __half22float2(v.c); cc2.x = fmaf(w, f.x, cc2.x); cc2.y = fmaf(w, f.y, cc2.y); \
    f = __half22float2(v.d); cc3.x = fmaf(w, f.x, cc3.x); cc3.y = fmaf(w, f.y, cc3.y); \
  }

// Gather core: two-phase. Phase A prefetches first PF csr entries to registers
// (independent loads), phase B issues up to PF independent table loads (predicated,
// fully unrolled, alternating accumulator banks), remainder uses the unroll-4 loop.
#define GATHER_CORE()                                                                \
  float2 c0 = {0.f, 0.f}, c1 = {0.f, 0.f}, c2 = {0.f, 0.f}, c3 = {0.f, 0.f};        \
  float2 d0 = {0.f, 0.f}, d1 = {0.f, 0.f}, d2 = {0.f, 0.f}, d3 = {0.f, 0.f};        \
  unsigned pr[PF];                                                                   \
  _Pragma("unroll") for (int i = 0; i < PF; ++i) { if (i < m) pr[i] = row[i]; }      \
  _Pragma("unroll") for (int i = 0; i < PF; ++i) {                                   \
    if (i < m) {                                                                     \
      if (i & 1) { ACC_EDGE(pr[i], d0, d1, d2, d3) }                                 \
      else       { ACC_EDGE(pr[i], c0, c1, c2, c3) }                                 \
    }                                                                                \
  }                                                                                  \
  int e = PF;                                                                        \
  for (; e + 3 < m; e += 4) {                                                        \
    unsigned p0 = row[e], p1 = row[e + 1], p2 = row[e + 2], p3 = row[e + 3];         \
    ACC_EDGE(p0, c0, c1, c2, c3)                                                     \
    ACC_EDGE(p1, d0, d1, d2, d3)                                                     \
    ACC_EDGE(p2, c0, c1, c2, c3)                                                     \
    ACC_EDGE(p3, d0, d1, d2, d3)                                                     \
  }                                                                                  \
  for (; e < m; ++e) { unsigned p = row[e]; ACC_EDGE(p, c0, c1, c2, c3) }            \
  c0.x += d0.x; c0.y += d0.y; c1.x += d1.x; c1.y += d1.y;                            \
  c2.x += d2.x; c2.y += d2.y; c3.x += d3.x; c3.y += d3.y;

// Layer-1 gather: 4 lanes/node, lane owns 16B slice. Epilogue: tanh+bias, fp16 out.
__global__ void k_gather1(const unsigned* __restrict__ csr, const int2* __restrict__ rc,
                          const float* __restrict__ dis, const __half2* __restrict__ hh,
                          const float* __restrict__ b1, __half2* __restrict__ outv, int n) {
  int gid = blockIdx.x * blockDim.x + threadIdx.x;
  int node = gid >> 2;
  if (node >= n) return;
  int q = (threadIdx.x & 3) * 4;          // this lane's half2 base (8 features)
  int2 r = rc[node];
  const unsigned* row = csr + r.x;
  int m = r.y;
  const __half2* tbl = hh + q;
  GATHER_CORE()
  float dd = dis[node];
  h2x4 own = *reinterpret_cast<const h2x4*>(hh + (size_t)node * 16 + q);
  __half2* op = outv + (size_t)node * 16 + q;
  float2 o0 = __half22float2(own.a), o1 = __half22float2(own.b);
  float2 o2 = __half22float2(own.c), o3 = __half22float2(own.d);
  const float4* bp = reinterpret_cast<const float4*>(b1 + q * 2);
  float4 ba = bp[0], bb = bp[1];
  op[0] = __floats2half2_rn(dd * tanhf(ba.x + dd * (c0.x + o0.x)),
                            dd * tanhf(ba.y + dd * (c0.y + o0.y)));
  op[1] = __floats2half2_rn(dd * tanhf(ba.z + dd * (c1.x + o1.x)),
                            dd * tanhf(ba.w + dd * (c1.y + o1.y)));
  op[2] = __floats2half2_rn(dd * tanhf(bb.x + dd * (c2.x + o2.x)),
                            dd * tanhf(bb.y + dd * (c2.y + o2.y)));
  op[3] = __floats2half2_rn(dd * tanhf(bb.z + dd * (c3.x + o3.x)),
                            dd * tanhf(bb.w + dd * (c3.y + o3.y)));
}

// Layer-2 gather FUSED with GEMM2: gather y (4 lanes/node, 8 vals each), shfl-share y
// within the 4-lane group (positional regs, runtime k-base), then out = y@W2 + b2.
__global__ void k_gather2g(const unsigned* __restrict__ csr, const int2* __restrict__ rc,
                           const float* __restrict__ dis, const __half2* __restrict__ hh,
                           const float* __restrict__ W2, const float* __restrict__ b2,
                           float* __restrict__ out, int n) {
  __shared__ float sW[32 * 128];  // 16 KB
  __shared__ float sB[128];
  for (int t = threadIdx.x; t < 32 * 128; t += blockDim.x) sW[t] = W2[t];
  if (threadIdx.x < 128) sB[threadIdx.x] = b2[threadIdx.x];
  __syncthreads();
  int gid = blockIdx.x * blockDim.x + threadIdx.x;
  int node = gid >> 2;
  if (node >= n) return;
  int lq = threadIdx.x & 3;               // lane's quarter
  int q = lq * 4;                         // half2 base
  int2 r = rc[node];
  const unsigned* row = csr + r.x;
  int m = r.y;
  const __half2* tbl = hh + q;
  GATHER_CORE()
  float dd = dis[node];
  h2x4 own = *reinterpret_cast<const h2x4*>(hh + (size_t)node * 16 + q);
  float2 o0 = __half22float2(own.a), o1 = __half22float2(own.b);
  float2 o2 = __half22float2(own.c), o3 = __half22float2(own.d);
  __half2 y0 = __floats2half2_rn(dd * (c0.x + o0.x), dd * (c0.y + o0.y));
  __half2 y1 = __floats2half2_rn(dd * (c1.x + o1.x), dd * (c1.y + o1.y));
  __half2 y2 = __floats2half2_rn(dd * (c2.x + o2.x), dd * (c2.y + o2.y));
  __half2 y3 = __floats2half2_rn(dd * (c3.x + o3.x), dd * (c3.y + o3.y));
  __half2 g1_0 = shfl_h2(y0, 1), g1_1 = shfl_h2(y1, 1), g1_2 = shfl_h2(y2, 1), g1_3 = shfl_h2(y3, 1);
  __half2 g2_0 = shfl_h2(y0, 2), g2_1 = shfl_h2(y1, 2), g2_2 = shfl_h2(y2, 2), g2_3 = shfl_h2(y3, 2);
  __half2 g3_0 = shfl_h2(y0, 3), g3_1 = shfl_h2(y1, 3), g3_2 = shfl_h2(y2, 3), g3_3 = shfl_h2(y3, 3);
  int g4 = lq * 4;  // output float4 base; chunks at j = g4 + qq*16 (conflict-free)
  float4 a[8];
#pragma unroll
  for (int qq = 0; qq < 8; ++qq) a[qq] = *reinterpret_cast<const float4*>(&sB[g4 + qq * 16]);
#define GEMM_GRP(kb, h0, h1, h2v, h3v)                                              \
  {                                                                                 \
    __half2 hv[4] = {h0, h1, h2v, h3v};                                             \
    _Pragma("unroll") for (int ii = 0; ii < 4; ++ii) {                              \
      float2 yv = __half22float2(hv[ii]);                                           \
      const float* w0 = &sW[((kb + ii) * 2) * 128 + g4];                            \
      const float* w1 = &sW[((kb + ii) * 2 + 1) * 128 + g4];                        \
      _Pragma("unroll") for (int qq = 0; qq < 8; ++qq) {                            \
        float4 wa = *reinterpret_cast<const float4*>(w0 + qq * 16);                 \
        float4 wb = *reinterpret_cast<const float4*>(w1 + qq * 16);                 \
        a[qq].x = fmaf(yv.x, wa.x, fmaf(yv.y, wb.x, a[qq].x));                      \
        a[qq].y = fmaf(yv.x, wa.y, fmaf(yv.y, wb.y, a[qq].y));                      \
        a[qq].z = fmaf(yv.x, wa.z, fmaf(yv.y, wb.z, a[qq].z));                      \
        a[qq].w = fmaf(yv.x, wa.w, fmaf(yv.y, wb.w, a[qq].w));                      \
      }                                                                             \
    }                                                                               \
  }
  GEMM_GRP(lq * 4, y0, y1, y2, y3)
  GEMM_GRP((lq ^ 1) * 4, g1_0, g1_1, g1_2, g1_3)
  GEMM_GRP((lq ^ 2) * 4, g2_0, g2_1, g2_2, g2_3)
  GEMM_GRP((lq ^ 3) * 4, g3_0, g3_1, g3_2, g3_3)
#undef GEMM_GRP
  float* op = out + (size_t)node * 128 + g4;
#pragma unroll
  for (int qq = 0; qq < 8; ++qq) *reinterpret_cast<float4*>(op + qq * 16) = a[qq];
}

static inline dim3 gx(long long work) { return dim3((unsigned)((work + TPB - 1) / TPB)); }

extern "C" void kernel_launch(void* const* d_in, const int* in_sizes, int n_in,
                              void* d_out, int out_size, void* d_ws, size_t ws_size,
                              hipStream_t stream) {
  const float* x   = (const float*)d_in[0];
  const int*   src = (const int*)d_in[1];
  const int*   dst = (const int*)d_in[2];
  const float* ew  = (const float*)d_in[3];
  const float* W1  = (const float*)d_in[4];
  const float* b1  = (const float*)d_in[5];
  const float* W2  = (const float*)d_in[6];
  const float* b2  = (const float*)d_in[7];
  float* out = (float*)d_out;

  const int n = in_sizes[0] / 45;  // 100000
  const int E = in_sizes[1];       // 1600000
  const int NB = (n + 255) >> NPB_SHIFT;  // 391 (<= 512)

  char* w = (char*)d_ws;
  size_t o = 0;
  auto alloc = [&](size_t bytes) { void* p = w + o; o += ((bytes + 255) & ~(size_t)255); return p; };
  int*           bkcnt = (int*)          alloc((size_t)NB * 4);
  unsigned*      ppk   = (unsigned*)     alloc((size_t)NB * BCAP * 4);  // 8 MB padded
  unsigned char* pld   = (unsigned char*)alloc((size_t)NB * BCAP);      // 2 MB padded
  unsigned*      csr   = (unsigned*)     alloc((size_t)NB * BCAP * 4);  // 8 MB padded
  int2*          rc    = (int2*)         alloc((size_t)n * 8);
  float*         dis   = (float*)        alloc((size_t)n * 4);
  __half2*       hh    = (__half2*)      alloc((size_t)n * 32 * 2);     // 6.4 MB
  __half2*       ag1   = (__half2*)      alloc((size_t)n * 32 * 2);     // 6.4 MB

  const int PB = (E + PCHUNK - 1) / PCHUNK;     // 391

  hipMemsetAsync(bkcnt, 0, (size_t)NB * 4, stream);
  k_partition<<<PB, TPB, 0, stream>>>(src, dst, ew, bkcnt, ppk, pld, E, NB);
  k_bucket<<<NB, TPB, 0, stream>>>(ppk, pld, bkcnt, csr, rc, dis, x, W1, hh, n);
  k_gather1<<<gx((long long)n * 4), TPB, 0, stream>>>(csr, rc, dis, hh, b1, ag1, n);
  k_gather2g<<<gx((long long)n * 4), TPB, 0, stream>>>(csr, rc, dis, ag1, W2, b2, out, n);
}

// Round 22
// 138.286 us; speedup vs baseline: 1.1205x; 1.0073x over previous
//
#include <hip/hip_runtime.h>
#include <hip/hip_fp16.h>
#include <math.h>

static constexpr int TPB = 256;
static constexpr int NPB_SHIFT = 8;   // 256 nodes per bucket (partition granularity)
static constexpr int BCAP = 5120;     // arrival region per bucket; Poisson(4096) + 16 sigma
static constexpr int HCAP = 2816;     // csr sub-region per half-bucket; Poisson(2048) + 17 sigma
static constexpr int CSTRIDE = 2 * HCAP;  // 5632 csr slots per bucket
static constexpr int PCHUNK = 4096;   // edges per partition block (16/thread)
static constexpr int PF = 16;         // csr register-prefetch depth

// pk = (src << 15) | (fp16_bits(ew) & 0x7FFF)   [ew >= 0, sign bit 0]
__device__ __forceinline__ int p_src(unsigned p) { return (int)(p >> 15); }
__device__ __forceinline__ float p_w(unsigned p) {
  return __half2float(__ushort_as_half((unsigned short)(p & 0x7FFFu)));
}

struct h2x4 { __half2 a, b, c, d; };  // 16B row slice

__device__ __forceinline__ __half2 shfl_h2(__half2 v, int mask) {
  int b = *reinterpret_cast<int*>(&v);
  int r = __shfl_xor(b, mask, 64);
  return *reinterpret_cast<__half2*>(&r);
}

// Each block bins PCHUNK edges into FIXED arrival regions [b*BCAP, b*BCAP+BCAP):
// LDS histogram -> one global atomic per touched bucket (private range) -> contiguous runs.
__global__ void k_partition(const int* __restrict__ src, const int* __restrict__ dst,
                            const float* __restrict__ ew, int* __restrict__ bkcnt,
                            unsigned* __restrict__ ppk, unsigned char* __restrict__ pld,
                            int E, int NB) {
  __shared__ int lh[512];
  __shared__ int lbase[512];
  __shared__ int lcur[512];
  int tid = threadIdx.x;
  long long e0 = (long long)blockIdx.x * PCHUNK;
  int d[PCHUNK / TPB];
  unsigned pk[PCHUNK / TPB];
  for (int t = tid; t < NB; t += TPB) { lh[t] = 0; lcur[t] = 0; }
  __syncthreads();
#pragma unroll
  for (int r = 0; r < PCHUNK / TPB; ++r) {
    long long e = e0 + (long long)r * TPB + tid;
    if (e < E) {
      d[r] = dst[e];
      pk[r] = ((unsigned)src[e] << 15) |
              ((unsigned)__half_as_ushort(__float2half(ew[e])) & 0x7FFFu);
      atomicAdd(&lh[d[r] >> NPB_SHIFT], 1);
    } else {
      d[r] = -1;
    }
  }
  __syncthreads();
  for (int t = tid; t < NB; t += TPB)
    lbase[t] = lh[t] ? (t * BCAP + atomicAdd(&bkcnt[t], lh[t])) : 0;
  __syncthreads();
#pragma unroll
  for (int r = 0; r < PCHUNK / TPB; ++r) {
    if (d[r] >= 0) {
      int b = d[r] >> NPB_SHIFT;
      int pos = atomicAdd(&lcur[b], 1);
      size_t gp = (size_t)lbase[b] + pos;   // run stays inside region (16-sigma margin)
      ppk[gp] = pk[r];
      pld[gp] = (unsigned char)(d[r] & 255);
    }
  }
}

// TWO blocks per bucket (half = 128 nodes each): each scans the bucket's arrival region
// (L2-hot), filters its half, builds CSR into its own fixed sub-region, computes dis,
// and does fused GEMM1+scale (2 threads/node). No LDS edge staging -> 7 KB LDS.
__global__ void __launch_bounds__(TPB) k_bucket(const unsigned* __restrict__ ppk,
                                                const unsigned char* __restrict__ pld,
                                                const int* __restrict__ bkcnt,
                                                unsigned* __restrict__ csr,
                                                int2* __restrict__ rc,
                                                float* __restrict__ dis,
                                                const float* __restrict__ x,
                                                const float* __restrict__ W1,
                                                __half2* __restrict__ hh, int n) {
  __shared__ float sW[45 * 32];        // 5.6 KB
  __shared__ int lcnt[128];
  __shared__ int lofs[128];
  __shared__ float lsum[128];
  int b = blockIdx.x >> 1;
  int half = blockIdx.x & 1;
  int t = threadIdx.x;
  int beg = b * BCAP;                       // arrival region
  int cbeg = b * CSTRIDE + half * HCAP;     // this half's csr sub-region
  int m = bkcnt[b];
  if (m > BCAP) m = BCAP;  // statistically impossible
  if (t < 128) { lcnt[t] = 0; lsum[t] = 0.f; }
  for (int i = t; i < 45 * 32; i += TPB) sW[i] = W1[i];
  __syncthreads();
  // Phase A: count this half's nodes
  for (int i = t; i < m; i += TPB) {
    int ld = pld[(size_t)beg + i];
    if ((ld >> 7) == half) atomicAdd(&lcnt[ld & 127], 1);
  }
  __syncthreads();
  int v = (t < 128) ? lcnt[t] : 0;
  if (t < 128) lofs[t] = v;
  __syncthreads();
  for (int off = 1; off < 128; off <<= 1) {  // inclusive scan over 128
    int tv = (t < 128 && t >= off) ? lofs[t - off] : 0;
    __syncthreads();
    if (t < 128) lofs[t] += tv;
    __syncthreads();
  }
  int gnode = (b << NPB_SHIFT) + half * 128 + t;  // valid for t<128
  if (t < 128) {
    int ex = lofs[t] - v;
    if (gnode < n) rc[gnode] = make_int2(cbeg + ex, v);
    lcnt[t] = ex;  // reuse as cursor
  }
  __syncthreads();
  // Phase B: scatter this half's edges into csr sub-region (arrival region is L2-hot)
  for (int i = t; i < m; i += TPB) {
    int ld = pld[(size_t)beg + i];
    if ((ld >> 7) == half) {
      unsigned pk = ppk[(size_t)beg + i];
      int pos = atomicAdd(&lcnt[ld & 127], 1);
      csr[(size_t)cbeg + pos] = pk;
      atomicAdd(&lsum[ld & 127], p_w(pk));
    }
  }
  __syncthreads();
  // Phase C: GEMM1 + scale, 2 threads per node (feature halves)
  int ln = t >> 1;        // local node 0..127
  int jh = t & 1;         // feature half: features [jh*16, jh*16+16)
  int gnode2 = (b << NPB_SHIFT) + half * 128 + ln;
  if (gnode2 < n) {
    float dsc = rsqrtf(1.0f + lsum[ln]);
    if (jh == 0) dis[gnode2] = dsc;
    float xr[45];
#pragma unroll
    for (int k = 0; k < 45; ++k) xr[k] = x[(size_t)gnode2 * 45 + k];
    __half2* hw = hh + (size_t)gnode2 * 16 + jh * 8;
#pragma unroll
    for (int j2 = 0; j2 < 8; ++j2) {
      int j = jh * 16 + j2 * 2;
      float a0 = 0.f, a1 = 0.f;
#pragma unroll
      for (int k = 0; k < 45; ++k) {
        a0 = fmaf(xr[k], sW[k * 32 + j], a0);
        a1 = fmaf(xr[k], sW[k * 32 + j + 1], a1);
      }
      hw[j2] = __floats2half2_rn(a0 * dsc, a1 * dsc);
    }
  }
}

// Accumulate macro shared by both gathers: one edge (pk) into bank (cc0..cc3).
#define ACC_EDGE(pk, cc0, cc1, cc2, cc3)                                             \
  {                                                                                  \
    h2x4 v = *reinterpret_cast<const h2x4*>(tbl + (size_t)p_src(pk) * 16);           \
    float w = p_w(pk);                                                               \
    float2 f;                                                                        \
    f = __half22float2(v.a); cc0.x = fmaf(w, f.x, cc0.x); cc0.y = fmaf(w, f.y, cc0.y); \
    f = __half22float2(v.b); cc1.x = fmaf(w, f.x, cc1.x); cc1.y = fmaf(w, f.y, cc1.y); \
    f = __half22float2(v.c); cc2.x = fmaf(w, f.x, cc2.x); cc2.y = fmaf(w, f.y, cc2.y); \
    f = __half22float2(v.d); cc3.x = fmaf(w, f.x, cc3.x); cc3.y = fmaf(w, f.y, cc3.y); \
  }

// Gather core: prefetch first PF csr entries to regs, issue up to PF independent table
// loads (predicated, unrolled, alternating banks), remainder via unroll-4 loop.
#define GATHER_CORE()                                                                \
  float2 c0 = {0.f, 0.f}, c1 = {0.f, 0.f}, c2 = {0.f, 0.f}, c3 = {0.f, 0.f};        \
  float2 d0 = {0.f, 0.f}, d1 = {0.f, 0.f}, d2 = {0.f, 0.f}, d3 = {0.f, 0.f};        \
  unsigned pr[PF];                                                                   \
  _Pragma("unroll") for (int i = 0; i < PF; ++i) { if (i < m) pr[i] = row[i]; }      \
  _Pragma("unroll") for (int i = 0; i < PF; ++i) {                                   \
    if (i < m) {                                                                     \
      if (i & 1) { ACC_EDGE(pr[i], d0, d1, d2, d3) }                                 \
      else       { ACC_EDGE(pr[i], c0, c1, c2, c3) }                                 \
    }                                                                                \
  }                                                                                  \
  int e = PF;                                                                        \
  for (; e + 3 < m; e += 4) {                                                        \
    unsigned p0 = row[e], p1 = row[e + 1], p2 = row[e + 2], p3 = row[e + 3];         \
    ACC_EDGE(p0, c0, c1, c2, c3)                                                     \
    ACC_EDGE(p1, d0, d1, d2, d3)                                                     \
    ACC_EDGE(p2, c0, c1, c2, c3)                                                     \
    ACC_EDGE(p3, d0, d1, d2, d3)                                                     \
  }                                                                                  \
  for (; e < m; ++e) { unsigned p = row[e]; ACC_EDGE(p, c0, c1, c2, c3) }            \
  c0.x += d0.x; c0.y += d0.y; c1.x += d1.x; c1.y += d1.y;                            \
  c2.x += d2.x; c2.y += d2.y; c3.x += d3.x; c3.y += d3.y;

// Layer-1 gather: 4 lanes/node, lane owns 16B slice. Epilogue: tanh+bias, fp16 out.
__global__ void k_gather1(const unsigned* __restrict__ csr, const int2* __restrict__ rc,
                          const float* __restrict__ dis, const __half2* __restrict__ hh,
                          const float* __restrict__ b1, __half2* __restrict__ outv, int n) {
  int gid = blockIdx.x * blockDim.x + threadIdx.x;
  int node = gid >> 2;
  if (node >= n) return;
  int q = (threadIdx.x & 3) * 4;          // this lane's half2 base (8 features)
  int2 r = rc[node];
  const unsigned* row = csr + r.x;
  int m = r.y;
  const __half2* tbl = hh + q;
  GATHER_CORE()
  float dd = dis[node];
  h2x4 own = *reinterpret_cast<const h2x4*>(hh + (size_t)node * 16 + q);
  __half2* op = outv + (size_t)node * 16 + q;
  float2 o0 = __half22float2(own.a), o1 = __half22float2(own.b);
  float2 o2 = __half22float2(own.c), o3 = __half22float2(own.d);
  const float4* bp = reinterpret_cast<const float4*>(b1 + q * 2);
  float4 ba = bp[0], bb = bp[1];
  op[0] = __floats2half2_rn(dd * tanhf(ba.x + dd * (c0.x + o0.x)),
                            dd * tanhf(ba.y + dd * (c0.y + o0.y)));
  op[1] = __floats2half2_rn(dd * tanhf(ba.z + dd * (c1.x + o1.x)),
                            dd * tanhf(ba.w + dd * (c1.y + o1.y)));
  op[2] = __floats2half2_rn(dd * tanhf(bb.x + dd * (c2.x + o2.x)),
                            dd * tanhf(bb.y + dd * (c2.y + o2.y)));
  op[3] = __floats2half2_rn(dd * tanhf(bb.z + dd * (c3.x + o3.x)),
                            dd * tanhf(bb.w + dd * (c3.y + o3.y)));
}

// Layer-2 gather FUSED with GEMM2: gather y (4 lanes/node, 8 vals each), shfl-share y
// within the 4-lane group (positional regs, runtime k-base), then out = y@W2 + b2.
__global__ void k_gather2g(const unsigned* __restrict__ csr, const int2* __restrict__ rc,
                           const float* __restrict__ dis, const __half2* __restrict__ hh,
                           const float* __restrict__ W2, const float* __restrict__ b2,
                           float* __restrict__ out, int n) {
  __shared__ float sW[32 * 128];  // 16 KB
  __shared__ float sB[128];
  for (int t = threadIdx.x; t < 32 * 128; t += blockDim.x) sW[t] = W2[t];
  if (threadIdx.x < 128) sB[threadIdx.x] = b2[threadIdx.x];
  __syncthreads();
  int gid = blockIdx.x * blockDim.x + threadIdx.x;
  int node = gid >> 2;
  if (node >= n) return;
  int lq = threadIdx.x & 3;               // lane's quarter
  int q = lq * 4;                         // half2 base
  int2 r = rc[node];
  const unsigned* row = csr + r.x;
  int m = r.y;
  const __half2* tbl = hh + q;
  GATHER_CORE()
  float dd = dis[node];
  h2x4 own = *reinterpret_cast<const h2x4*>(hh + (size_t)node * 16 + q);
  float2 o0 = __half22float2(own.a), o1 = __half22float2(own.b);
  float2 o2 = __half22float2(own.c), o3 = __half22float2(own.d);
  __half2 y0 = __floats2half2_rn(dd * (c0.x + o0.x), dd * (c0.y + o0.y));
  __half2 y1 = __floats2half2_rn(dd * (c1.x + o1.x), dd * (c1.y + o1.y));
  __half2 y2 = __floats2half2_rn(dd * (c2.x + o2.x), dd * (c2.y + o2.y));
  __half2 y3 = __floats2half2_rn(dd * (c3.x + o3.x), dd * (c3.y + o3.y));
  __half2 g1_0 = shfl_h2(y0, 1), g1_1 = shfl_h2(y1, 1), g1_2 = shfl_h2(y2, 1), g1_3 = shfl_h2(y3, 1);
  __half2 g2_0 = shfl_h2(y0, 2), g2_1 = shfl_h2(y1, 2), g2_2 = shfl_h2(y2, 2), g2_3 = shfl_h2(y3, 2);
  __half2 g3_0 = shfl_h2(y0, 3), g3_1 = shfl_h2(y1, 3), g3_2 = shfl_h2(y2, 3), g3_3 = shfl_h2(y3, 3);
  int g4 = lq * 4;  // output float4 base; chunks at j = g4 + qq*16 (conflict-free)
  float4 a[8];
#pragma unroll
  for (int qq = 0; qq < 8; ++qq) a[qq] = *reinterpret_cast<const float4*>(&sB[g4 + qq * 16]);
#define GEMM_GRP(kb, h0, h1, h2v, h3v)                                              \
  {                                                                                 \
    __half2 hv[4] = {h0, h1, h2v, h3v};                                             \
    _Pragma("unroll") for (int ii = 0; ii < 4; ++ii) {                              \
      float2 yv = __half22float2(hv[ii]);                                           \
      const float* w0 = &sW[((kb + ii) * 2) * 128 + g4];                            \
      const float* w1 = &sW[((kb + ii) * 2 + 1) * 128 + g4];                        \
      _Pragma("unroll") for (int qq = 0; qq < 8; ++qq) {                            \
        float4 wa = *reinterpret_cast<const float4*>(w0 + qq * 16);                 \
        float4 wb = *reinterpret_cast<const float4*>(w1 + qq * 16);                 \
        a[qq].x = fmaf(yv.x, wa.x, fmaf(yv.y, wb.x, a[qq].x));                      \
        a[qq].y = fmaf(yv.x, wa.y, fmaf(yv.y, wb.y, a[qq].y));                      \
        a[qq].z = fmaf(yv.x, wa.z, fmaf(yv.y, wb.z, a[qq].z));                      \
        a[qq].w = fmaf(yv.x, wa.w, fmaf(yv.y, wb.w, a[qq].w));                      \
      }                                                                             \
    }                                                                               \
  }
  GEMM_GRP(lq * 4, y0, y1, y2, y3)
  GEMM_GRP((lq ^ 1) * 4, g1_0, g1_1, g1_2, g1_3)
  GEMM_GRP((lq ^ 2) * 4, g2_0, g2_1, g2_2, g2_3)
  GEMM_GRP((lq ^ 3) * 4, g3_0, g3_1, g3_2, g3_3)
#undef GEMM_GRP
  float* op = out + (size_t)node * 128 + g4;
#pragma unroll
  for (int qq = 0; qq < 8; ++qq) *reinterpret_cast<float4*>(op + qq * 16) = a[qq];
}

static inline dim3 gx(long long work) { return dim3((unsigned)((work + TPB - 1) / TPB)); }

extern "C" void kernel_launch(void* const* d_in, const int* in_sizes, int n_in,
                              void* d_out, int out_size, void* d_ws, size_t ws_size,
                              hipStream_t stream) {
  const float* x   = (const float*)d_in[0];
  const int*   src = (const int*)d_in[1];
  const int*   dst = (const int*)d_in[2];
  const float* ew  = (const float*)d_in[3];
  const float* W1  = (const float*)d_in[4];
  const float* b1  = (const float*)d_in[5];
  const float* W2  = (const float*)d_in[6];
  const float* b2  = (const float*)d_in[7];
  float* out = (float*)d_out;

  const int n = in_sizes[0] / 45;  // 100000
  const int E = in_sizes[1];       // 1600000
  const int NB = (n + 255) >> NPB_SHIFT;  // 391 (<= 512)

  char* w = (char*)d_ws;
  size_t o = 0;
  auto alloc = [&](size_t bytes) { void* p = w + o; o += ((bytes + 255) & ~(size_t)255); return p; };
  int*           bkcnt = (int*)          alloc((size_t)NB * 4);
  unsigned*      ppk   = (unsigned*)     alloc((size_t)NB * BCAP * 4);     // 8 MB arrival
  unsigned char* pld   = (unsigned char*)alloc((size_t)NB * BCAP);         // 2 MB arrival
  unsigned*      csr   = (unsigned*)     alloc((size_t)NB * CSTRIDE * 4);  // 8.8 MB padded
  int2*          rc    = (int2*)         alloc((size_t)n * 8);
  float*         dis   = (float*)        alloc((size_t)n * 4);
  __half2*       hh    = (__half2*)      alloc((size_t)n * 32 * 2);        // 6.4 MB
  __half2*       ag1   = (__half2*)      alloc((size_t)n * 32 * 2);        // 6.4 MB

  const int PB = (E + PCHUNK - 1) / PCHUNK;     // 391

  hipMemsetAsync(bkcnt, 0, (size_t)NB * 4, stream);
  k_partition<<<PB, TPB, 0, stream>>>(src, dst, ew, bkcnt, ppk, pld, E, NB);
  k_bucket<<<NB * 2, TPB, 0, stream>>>(ppk, pld, bkcnt, csr, rc, dis, x, W1, hh, n);
  k_gather1<<<gx((long long)n * 4), TPB, 0, stream>>>(csr, rc, dis, hh, b1, ag1, n);
  k_gather2g<<<gx((long long)n * 4), TPB, 0, stream>>>(csr, rc, dis, ag1, W2, b2, out, n);
}